// Round 3
// baseline (400.606 us; speedup 1.0000x reference)
//
#include <hip/hip_runtime.h>
#include <stdint.h>

#define NGK   5
#define NFK   10
#define NWK   8
#define STEPW 16      // NG + NF + 1
#define NSEQ  512
#define FDIM  32
#define NPK   16      // packed half2 regs per row (32 halves)
#define BIGV  1000000000.0f

typedef _Float16 h2 __attribute__((ext_vector_type(2)));

union U32H2 { uint32_t u; h2 h; };
union U32F  { uint32_t u; float f; };

__device__ __forceinline__ h2 as_h2(uint32_t u) { U32H2 c; c.u = u; return c.h; }
__device__ __forceinline__ uint32_t as_u32(h2 h) { U32H2 c; c.h = h; return c.u; }

// packed-f16 dot of two 32-element rows (16 packed regs), f32 result.
__device__ __forceinline__ float dot_row(const uint32_t* a, const uint32_t* b) {
    h2 a0 = (h2)(_Float16)0, a1 = (h2)(_Float16)0, a2 = (h2)(_Float16)0, a3 = (h2)(_Float16)0;
    #pragma unroll
    for (int c = 0; c < NPK; c += 4) {
        a0 += as_h2(a[c + 0]) * as_h2(b[c + 0]);
        a1 += as_h2(a[c + 1]) * as_h2(b[c + 1]);
        a2 += as_h2(a[c + 2]) * as_h2(b[c + 2]);
        a3 += as_h2(a[c + 3]) * as_h2(b[c + 3]);
    }
    h2 s = (a0 + a1) + (a2 + a3);
    return (float)s.x + (float)s.y;
}

// lane n <- lane n-1 within the 64-lane wave (DPP wave_shr:1, ctrl 0x138).
// lane 0 gets 0 (bound_ctrl) and is always overwritten explicitly.
__device__ __forceinline__ uint32_t dpp_shr1_u(uint32_t v) {
    return (uint32_t)__builtin_amdgcn_update_dpp(0, (int)v, 0x138, 0xF, 0xF, true);
}
__device__ __forceinline__ float dpp_shr1_f(float v) {
    U32F c; c.f = v;
    c.u = dpp_shr1_u(c.u);
    return c.f;
}

// One block (512 threads = 8 waves) per batch element. Thread i owns DP row i.
// x-rows and the R recursion flow up the lanes via DPP; LDS only for the
// cross-wave R boundary (1 float/wave/step, double-buffered) and lane-0
// fresh-row prefetch (4x ds_read_b128, one step ahead).
__global__ __launch_bounds__(512, 2) void sdtw_kernel(
    const float* __restrict__ data, const int* __restrict__ lens,
    float* __restrict__ dists)
{
    __shared__ __align__(16) uint32_t LXh[NSEQ][NPK];  // 32 KB, f16-packed rows
    __shared__ float LSQ[NSEQ];                        // 2 KB
    __shared__ float BND[2][NWK];                      // cross-wave R boundary

    const int b = blockIdx.x;
    const int t = threadIdx.x;
    const int wid = t >> 6;
    const int wlane = t & 63;
    const int i = t;
    const float* xb = data + (size_t)b * (NSEQ * FDIM);

    // ---- stage: coalesced float4 global loads -> f16 pack -> LDS ----
    #pragma unroll
    for (int r = 0; r < 8; ++r) {
        int q = r * 512 + t;               // float4 index, 4096 total
        float4 v = ((const float4*)xb)[q];
        h2 p0; p0.x = (_Float16)v.x; p0.y = (_Float16)v.y;
        h2 p1; p1.x = (_Float16)v.z; p1.y = (_Float16)v.w;
        int row = q >> 3, c2 = (q & 7) * 2;
        LXh[row][c2]     = as_u32(p0);
        LXh[row][c2 + 1] = as_u32(p1);
    }
    __syncthreads();

    // ---- own row into registers; squared norm (same instr sequence as dot) ----
    uint32_t xi[NPK];
    #pragma unroll
    for (int c = 0; c < NPK; ++c) xi[c] = LXh[i][c];
    float sqi = dot_row(xi, xi);
    LSQ[i] = sqi;

    int L = lens[b];
    L = L < 1 ? 1 : (L > NSEQ ? NSEQ : L);

    // DP state: r1 = R_{k-1}[i], s1p = R_{k-1}[i-1] from previous step (=s2 next step)
    float r1  = (i == 0) ? 0.0f : BIGV;   // R_0: D[0][0] == 0 exactly here
    float s1p = BIGV;

    if (wlane == 63) BND[0][wid] = r1;
    __syncthreads();

    // ---- x pipeline init (k = 0 state) + prefetch for first active step ----
    uint32_t xj[NPK]; float sqj = 0.f;
    uint32_t xp[NPK]; float sqp = 0.f;
    if (wlane == 0) {
        // at first active step k = i, lane 0 needs row j = 0 (prefetched in xp);
        // wave 0's lane 0 first steps at k=1 -> row 1.
        uint4 v0 = *(const uint4*)&LXh[0][0];
        uint4 v1 = *(const uint4*)&LXh[0][4];
        uint4 v2 = *(const uint4*)&LXh[0][8];
        uint4 v3 = *(const uint4*)&LXh[0][12];
        xj[0]=v0.x; xj[1]=v0.y; xj[2]=v0.z; xj[3]=v0.w;
        xj[4]=v1.x; xj[5]=v1.y; xj[6]=v1.z; xj[7]=v1.w;
        xj[8]=v2.x; xj[9]=v2.y; xj[10]=v2.z; xj[11]=v2.w;
        xj[12]=v3.x; xj[13]=v3.y; xj[14]=v3.z; xj[15]=v3.w;
        sqj = LSQ[0];
        int jn = 1 - i; jn = jn < 0 ? 0 : jn;   // row 1 for wave 0, row 0 otherwise
        uint4 p0 = *(const uint4*)&LXh[jn][0];
        uint4 p1 = *(const uint4*)&LXh[jn][4];
        uint4 p2 = *(const uint4*)&LXh[jn][8];
        uint4 p3 = *(const uint4*)&LXh[jn][12];
        xp[0]=p0.x; xp[1]=p0.y; xp[2]=p0.z; xp[3]=p0.w;
        xp[4]=p1.x; xp[5]=p1.y; xp[6]=p1.z; xp[7]=p1.w;
        xp[8]=p2.x; xp[9]=p2.y; xp[10]=p2.z; xp[11]=p2.w;
        xp[12]=p3.x; xp[13]=p3.y; xp[14]=p3.z; xp[15]=p3.w;
        sqp = LSQ[jn];
    } else {
        #pragma unroll
        for (int c = 0; c < NPK; ++c) { xj[c] = 0u; xp[c] = 0u; }
    }

    const int kend  = 2 * L - 2;
    const int wbase = wid * 64;
    const int wlast = wbase + 63 + (L - 1);
    const bool wrun = (wbase < L);          // wave contains at least one valid row

    const float INVGL = 0.28853900817779268f;   // 1/(gamma*ln2)
    const float GLN2  = 3.4657359027997265f;    // gamma*ln2

    for (int k = 1; k <= kend; ++k) {
        if (wrun && k >= wbase && k <= wlast) {
            // shift pipelines one lane up (wave-uniform DPP)
            uint32_t nx[NPK];
            #pragma unroll
            for (int c = 0; c < NPK; ++c) nx[c] = dpp_shr1_u(xj[c]);
            float s1  = dpp_shr1_f(r1);
            float nsq = dpp_shr1_f(sqj);
            const int j = k - i;
            if (wlane == 0) {
                // apply prefetched row for this step
                #pragma unroll
                for (int c = 0; c < NPK; ++c) nx[c] = xp[c];
                nsq = sqp;
                // cross-wave R boundary: cell (i-1, j); mask staleness explicitly
                bool okp = (i > 0) && (j >= 0) && (j < L) && (i <= L);
                float bv = BND[(k - 1) & 1][(wid - 1) & (NWK - 1)];
                s1 = okp ? bv : BIGV;
                // prefetch row for next step (latency hidden behind this step)
                int jn = j + 1; jn = jn < 0 ? 0 : (jn > NSEQ - 1 ? NSEQ - 1 : jn);
                uint4 p0 = *(const uint4*)&LXh[jn][0];
                uint4 p1 = *(const uint4*)&LXh[jn][4];
                uint4 p2 = *(const uint4*)&LXh[jn][8];
                uint4 p3 = *(const uint4*)&LXh[jn][12];
                xp[0]=p0.x; xp[1]=p0.y; xp[2]=p0.z; xp[3]=p0.w;
                xp[4]=p1.x; xp[5]=p1.y; xp[6]=p1.z; xp[7]=p1.w;
                xp[8]=p2.x; xp[9]=p2.y; xp[10]=p2.z; xp[11]=p2.w;
                xp[12]=p3.x; xp[13]=p3.y; xp[14]=p3.z; xp[15]=p3.w;
                sqp = LSQ[jn];
            }
            #pragma unroll
            for (int c = 0; c < NPK; ++c) xj[c] = nx[c];
            sqj = nsq;

            // D[i][j] on the fly (packed f16 dot)
            float dt = dot_row(xi, xj);
            float Dij = sqi + sqj - 2.0f * dt;

            // softmin(s2, s1, r1): s2 == s1 from previous step (s1p)
            float m = fminf(fminf(s1p, s1), r1);
            float e = __builtin_amdgcn_exp2f((m - s1p) * INVGL)
                    + __builtin_amdgcn_exp2f((m - s1 ) * INVGL)
                    + __builtin_amdgcn_exp2f((m - r1 ) * INVGL);
            float rn = Dij + m - GLN2 * __builtin_amdgcn_logf(e);

            bool valid = (j >= 0) && (j < L) && (i < L);
            rn = valid ? rn : BIGV;
            s1p = s1;
            r1  = rn;
            if (wlane == 63) BND[k & 1][wid] = r1;
        }
        __syncthreads();
    }

    if (i == L - 1) dists[b] = r1 * (0.5f / (float)L);
}

// Tiny finalize: hard-triplet reduction over the 128 distances -> scalar
__global__ __launch_bounds__(64) void finalize_kernel(
    const float* __restrict__ dists, float* __restrict__ out)
{
    __shared__ float acc[NWK];
    const int t = threadIdx.x;
    const int g = NGK + 1;  // 6
    if (t < NWK) {
        float dd[STEPW];
        #pragma unroll
        for (int s = 0; s < STEPW; ++s) dd[s] = dists[t * STEPW + s];

        float sum_lks = 0.f, nnz = 0.f;
        for (int ii = 0; ii < g; ++ii) {
            float mx = 0.f;  // scores are relu'd (>=0), so 0 is a safe identity
            for (int jj = 0; jj < g; ++jj) {
                float dmg_ij = 0.5f * (dd[ii] + dd[jj]);
                for (int f = 0; f < NFK; ++f) {
                    float s = dmg_ij + 1.0f - 0.5f * (dd[ii] + dd[g + f]);
                    s = fmaxf(s, 0.f);
                    mx = fmaxf(mx, s);
                }
            }
            sum_lks += mx;
            nnz += (mx != 0.f) ? 1.f : 0.f;
        }
        sum_lks *= (float)(g * NFK);
        nnz     *= (float)(g * NFK);
        float lv = sum_lks / (nnz + 1.f);

        float only_pos = 0.f;
        for (int ii = 1; ii < g; ++ii)
            for (int jj = 0; jj < ii; ++jj)
                only_pos += 0.5f * (dd[ii] + dd[jj]);
        only_pos *= (0.01f / (float)NGK);  // MODEL_LAMBDA / NG

        acc[t] = lv + only_pos;
    }
    __syncthreads();
    if (t == 0) {
        float s = 0.f;
        #pragma unroll
        for (int w = 0; w < NWK; ++w) s += acc[w];
        out[0] = s * (1.0f / (float)NWK);
    }
}

extern "C" void kernel_launch(void* const* d_in, const int* in_sizes, int n_in,
                              void* d_out, int out_size, void* d_ws, size_t ws_size,
                              hipStream_t stream)
{
    const float* data = (const float*)d_in[0];   // (128, 512, 32) f32
    const int*   lens = (const int*)d_in[1];     // (128,) i32
    float* out   = (float*)d_out;                // scalar f32
    float* dists = (float*)d_ws;                 // 128 floats scratch

    const int B = NWK * STEPW;  // 128
    sdtw_kernel<<<B, 512, 0, stream>>>(data, lens, dists);
    finalize_kernel<<<1, 64, 0, stream>>>(dists, out);
}

// Round 4
// 317.427 us; speedup vs baseline: 1.2620x; 1.2620x over previous
//
#include <hip/hip_runtime.h>
#include <stdint.h>

#define NGK   5
#define NFK   10
#define NWK   8
#define STEPW 16      // NG + NF + 1
#define NSEQ  512
#define FDIM  32
#define BIGV  1000000000.0f
#define XSTR  20      // u32 stride per x-row in LDS (80 B; 16B-aligned, low-conflict)
#define DTPAD 17      // D-tile row stride in f32 (pad 16 -> 17 breaks bank conflicts)
#define DTILE (16 * DTPAD)   // 272 f32 per tile
#define DDIAG (32 * DTILE)   // 8704 f32 per tile-diagonal buffer

typedef short bf16x8 __attribute__((ext_vector_type(8)));  // 8 bf16 = 4 VGPR
typedef float f32x4  __attribute__((ext_vector_type(4)));

union U32F { uint32_t u; float f; };

__device__ __forceinline__ uint32_t f2bf(float f) {  // f32 -> bf16 (RNE)
    U32F c; c.f = f;
    return (c.u + 0x7FFFu + ((c.u >> 16) & 1u)) >> 16;
}
__device__ __forceinline__ float bfbits_lo(uint32_t u) { U32F c; c.u = u << 16; return c.f; }
__device__ __forceinline__ float bfbits_hi(uint32_t u) { U32F c; c.u = u & 0xFFFF0000u; return c.f; }

// lane n <- lane n-1 (DPP wave_shr:1 = 0x138); lane 0 -> 0, always overwritten.
__device__ __forceinline__ float dpp_shr1_f(float v) {
    U32F c; c.f = v;
    c.u = (uint32_t)__builtin_amdgcn_update_dpp(0, (int)c.u, 0x138, 0xF, 0xF, true);
    return c.f;
}

// One block (512 threads = 8 waves) per batch element. Thread i owns DP row i.
// D is generated tile-diagonal-by-tile-diagonal with 16x16x32 bf16 MFMA into a
// double-buffered LDS store; the DP step is then 1 ds_read + softmin + DPP.
__global__ __launch_bounds__(512, 1) void sdtw_kernel(
    const float* __restrict__ data, const int* __restrict__ lens,
    float* __restrict__ dists)
{
    __shared__ __align__(16) uint32_t LXh[NSEQ * XSTR];  // 40960 B, bf16-pair rows
    __shared__ __align__(16) float LSQ[NSEQ];            // 2 KB
    __shared__ __align__(16) float DS[2 * DDIAG];        // 69632 B, D tile-diags
    __shared__ float BND[2][NWK];                        // cross-wave R boundary

    const int b = blockIdx.x;
    const int t = threadIdx.x;
    const int wid = t >> 6;
    const int wlane = t & 63;
    const int i = t;
    const float* xb = data + (size_t)b * (NSEQ * FDIM);

    // ---- stage: coalesced float4 loads -> bf16 pack -> LDS ----
    #pragma unroll
    for (int r = 0; r < 8; ++r) {
        int q = r * 512 + t;               // float4 index, 4096 total
        float4 v = ((const float4*)xb)[q];
        int row = q >> 3, c2 = (q & 7) * 2;
        LXh[row * XSTR + c2]     = f2bf(v.x) | (f2bf(v.y) << 16);
        LXh[row * XSTR + c2 + 1] = f2bf(v.z) | (f2bf(v.w) << 16);
    }
    __syncthreads();

    // ---- LSQ[i]: f32 sum of squares of the SAME bf16 values MFMA consumes ----
    {
        float acc = 0.f;
        #pragma unroll
        for (int c = 0; c < 4; ++c) {
            uint4 u4 = *(const uint4*)&LXh[i * XSTR + c * 4];
            uint32_t us[4] = {u4.x, u4.y, u4.z, u4.w};
            #pragma unroll
            for (int e = 0; e < 4; ++e) {
                float lo = bfbits_lo(us[e]), hi = bfbits_hi(us[e]);
                acc = fmaf(lo, lo, acc);
                acc = fmaf(hi, hi, acc);
            }
        }
        LSQ[i] = acc;
    }

    int L = lens[b];
    L = L < 1 ? 1 : (L > NSEQ ? NSEQ : L);

    // DP state: r1 = R_{k-1}[i], s1p = R_{k-2}[i-1] (prev step's s1)
    float r1  = (i == 0) ? 0.0f : BIGV;   // R_0[0] = D[0][0] ~ 0
    float s1p = BIGV;
    if (wlane == 63) BND[0][wid] = r1;
    __syncthreads();

    const int kend = 2 * L - 2;
    const int M = (kend >> 4) + 1;        // 16-diagonal blocks
    const int ti = i >> 4;
    const int ibase = ti * DTILE + (i & 15) * DTPAD;  // u32 index within a parity buf
    const bool irun = (i < L);

    const float INVGL = 0.28853900817779268f;   // 1/(gamma*ln2)
    const float GLN2  = 3.4657359027997265f;    // gamma*ln2

    for (int m = 0; m < M; ++m) {
        // ---- generate D tile-diagonal m into parity buffer m&1 (MFMA) ----
        {
            int tlo = m - 31; if (tlo < 0) tlo = 0;
            int thi = (m < 31) ? m : 31;
            float* Dd = &DS[(m & 1) * DDIAG];
            const char* lx = (const char*)LXh;
            const int koff = (wlane >> 4) * 16;       // 16B k-slice within row
            const int rl = wlane & 15;
            for (int tix = tlo + wid; tix <= thi; tix += NWK) {
                int tjx = m - tix;
                if (tix * 16 < L && tjx * 16 < L) {
                    bf16x8 af = *(const bf16x8*)(lx + (tix * 16 + rl) * 80 + koff);
                    bf16x8 bg = *(const bf16x8*)(lx + (tjx * 16 + rl) * 80 + koff);
                    f32x4 cf = {0.f, 0.f, 0.f, 0.f};
                    cf = __builtin_amdgcn_mfma_f32_16x16x32_bf16(af, bg, cf, 0, 0, 0);
                    // C[row][col]: col = lane&15, row = (lane>>4)*4 + reg
                    float sqj = LSQ[tjx * 16 + rl];
                    f32x4 sq4 = *(const f32x4*)&LSQ[tix * 16 + ((wlane >> 4) << 2)];
                    float* drow = &Dd[tix * DTILE];
                    int rr0 = (wlane >> 4) * 4;
                    #pragma unroll
                    for (int q2 = 0; q2 < 4; ++q2) {
                        float dv = sq4[q2] + sqj - 2.0f * cf[q2];
                        drow[(rr0 + q2) * DTPAD + rl] = dv;
                    }
                }
            }
        }
        __syncthreads();

        // ---- 16 DP steps; D read software-pipelined one step ahead ----
        const int j0 = 16 * m - i;                    // j at kk=0
        float Dnext;
        {
            int j = j0;
            int p = (ti + (j >> 4)) & 1;
            Dnext = DS[p * DDIAG + ibase + (j & 15)];
        }
        #pragma unroll
        for (int kk = 0; kk < 16; ++kk) {
            const int k = 16 * m + kk;
            float Dv = Dnext;
            if (kk < 15) {                            // next D is in current window
                int j = j0 + kk + 1;
                int p = (ti + (j >> 4)) & 1;
                Dnext = DS[p * DDIAG + ibase + (j & 15)];
            }
            if (k >= 1 && k <= kend) {                // block-uniform guard
                int j = j0 + kk;                      // = k - i
                float s1 = dpp_shr1_f(r1);            // R_{k-1}[i-1] within wave
                float bv = BND[(k - 1) & 1][(wid - 1) & (NWK - 1)];  // broadcast read
                if (wlane == 0) s1 = (wid == 0) ? BIGV : bv;
                float mm = fminf(fminf(s1p, s1), r1);
                float e = __builtin_amdgcn_exp2f((mm - s1p) * INVGL)
                        + __builtin_amdgcn_exp2f((mm - s1 ) * INVGL)
                        + __builtin_amdgcn_exp2f((mm - r1 ) * INVGL);
                float rn = Dv + mm - GLN2 * __builtin_amdgcn_logf(e);
                bool valid = irun && ((uint32_t)j < (uint32_t)L);
                rn = valid ? rn : BIGV;
                s1p = s1;
                r1  = rn;
                if (wlane == 63) BND[k & 1][wid] = r1;
            }
            __syncthreads();
        }
    }

    if (i == L - 1) dists[b] = r1 * (0.5f / (float)L);
}

// Tiny finalize: hard-triplet reduction over the 128 distances -> scalar
__global__ __launch_bounds__(64) void finalize_kernel(
    const float* __restrict__ dists, float* __restrict__ out)
{
    __shared__ float acc[NWK];
    const int t = threadIdx.x;
    const int g = NGK + 1;  // 6
    if (t < NWK) {
        float dd[STEPW];
        #pragma unroll
        for (int s = 0; s < STEPW; ++s) dd[s] = dists[t * STEPW + s];

        float sum_lks = 0.f, nnz = 0.f;
        for (int ii = 0; ii < g; ++ii) {
            float mx = 0.f;  // scores are relu'd (>=0), so 0 is a safe identity
            for (int jj = 0; jj < g; ++jj) {
                float dmg_ij = 0.5f * (dd[ii] + dd[jj]);
                for (int f = 0; f < NFK; ++f) {
                    float s = dmg_ij + 1.0f - 0.5f * (dd[ii] + dd[g + f]);
                    s = fmaxf(s, 0.f);
                    mx = fmaxf(mx, s);
                }
            }
            sum_lks += mx;
            nnz += (mx != 0.f) ? 1.f : 0.f;
        }
        sum_lks *= (float)(g * NFK);
        nnz     *= (float)(g * NFK);
        float lv = sum_lks / (nnz + 1.f);

        float only_pos = 0.f;
        for (int ii = 1; ii < g; ++ii)
            for (int jj = 0; jj < ii; ++jj)
                only_pos += 0.5f * (dd[ii] + dd[jj]);
        only_pos *= (0.01f / (float)NGK);  // MODEL_LAMBDA / NG

        acc[t] = lv + only_pos;
    }
    __syncthreads();
    if (t == 0) {
        float s = 0.f;
        #pragma unroll
        for (int w = 0; w < NWK; ++w) s += acc[w];
        out[0] = s * (1.0f / (float)NWK);
    }
}

extern "C" void kernel_launch(void* const* d_in, const int* in_sizes, int n_in,
                              void* d_out, int out_size, void* d_ws, size_t ws_size,
                              hipStream_t stream)
{
    const float* data = (const float*)d_in[0];   // (128, 512, 32) f32
    const int*   lens = (const int*)d_in[1];     // (128,) i32
    float* out   = (float*)d_out;                // scalar f32
    float* dists = (float*)d_ws;                 // 128 floats scratch

    const int B = NWK * STEPW;  // 128
    sdtw_kernel<<<B, 512, 0, stream>>>(data, lens, dists);
    finalize_kernel<<<1, 64, 0, stream>>>(dists, out);
}